// Round 1
// baseline (831.046 us; speedup 1.0000x reference)
//
#include <hip/hip_runtime.h>

typedef _Float16 half8 __attribute__((ext_vector_type(8)));
typedef float f32x4 __attribute__((ext_vector_type(4)));

#define WPAD 264   // 256 + 8 f16 pad: keeps 16B alignment, breaks bank alignment

__device__ __forceinline__ void gload_lds16(const _Float16* g, _Float16* l) {
    __builtin_amdgcn_global_load_lds(
        (__attribute__((address_space(1))) void*)(void*)(g),
        (__attribute__((address_space(3))) void*)(void*)(l), 16, 0, 0);
}

// Repack W1..W4 fp32 [256x256] row-major -> f16 chunk-major [kc][n][kl] (kc=k/32, kl=k%32)
// so each 16KB K-chunk is contiguous for global_load_lds staging.
__global__ void convert_weights(const float* __restrict__ W1, const float* __restrict__ W2,
                                const float* __restrict__ W3, const float* __restrict__ W4,
                                _Float16* __restrict__ Wc) {
    int tid = blockIdx.x * 256 + threadIdx.x;      // 0 .. 262143
    int l   = tid >> 16;
    int rem = tid & 65535;
    int n = rem >> 8, k = rem & 255;
    const float* W = (l == 0) ? W1 : (l == 1) ? W2 : (l == 2) ? W3 : W4;
    int kc = k >> 5, kl = k & 31;
    Wc[l * 65536 + kc * 8192 + n * 32 + kl] = (_Float16)W[rem];
}

__launch_bounds__(256, 2)
__global__ void siren_fused(const float* __restrict__ xyt,
                            const float* __restrict__ W0,
                            const float* __restrict__ b0,
                            const _Float16* __restrict__ Wc,
                            const float* __restrict__ b1,
                            const float* __restrict__ b2,
                            const float* __restrict__ b3,
                            const float* __restrict__ b4,
                            const float* __restrict__ Wf,
                            const float* __restrict__ bfin,
                            float* __restrict__ out)
{
    __shared__ _Float16 hbuf[64 * WPAD];   // activations, 33 KB
    __shared__ _Float16 wlds[256 * 32];    // W K-chunk [n][kl], 16 KB
    __shared__ float    wf_s[256];
    __shared__ float    xs[192];

    const int tid  = threadIdx.x;
    const int lane = tid & 63;
    const int wv   = tid >> 6;       // wave 0..3
    const int mh   = wv & 1;         // M-half (32 rows)
    const int nh   = wv >> 1;        // N-half (128 cols)
    const int l15  = lane & 15;
    const int l4   = lane >> 4;
    const int gm0  = blockIdx.x * 64;

    if (tid < 192) xs[tid] = xyt[gm0 * 3 + tid];
    wf_s[tid] = Wf[tid];
    __syncthreads();

    // ---- layer 0: h = sin(30*(x @ W0^T + b0)), K=3, fp32 VALU ----
    {
        const int n = tid;
        const float w0x = W0[n * 3 + 0], w0y = W0[n * 3 + 1], w0z = W0[n * 3 + 2];
        const float bb = b0[n];
        #pragma unroll 4
        for (int m = 0; m < 64; ++m) {
            float z = 30.0f * fmaf(w0x, xs[m * 3],
                          fmaf(w0y, xs[m * 3 + 1],
                          fmaf(w0z, xs[m * 3 + 2], bb)));
            hbuf[m * WPAD + n] = (_Float16)__sinf(z);
        }
    }
    __syncthreads();

    const float* biases[4] = {b1, b2, b3, b4};

    // ---- 4 hidden layers: h = sin(h @ W^T + b), MFMA f16 ----
    for (int l = 0; l < 4; ++l) {
        // Preload this wave's full A (its 32 rows x K=256) into registers.
        // A-frag mapping (16x16x32): A[m=lane&15][k=(lane>>4)*8 + j]
        half8 afr[2][8];
        #pragma unroll
        for (int t = 0; t < 2; ++t)
            #pragma unroll
            for (int kc = 0; kc < 8; ++kc)
                afr[t][kc] = *(const half8*)&hbuf[(mh * 32 + t * 16 + l15) * WPAD + kc * 32 + l4 * 8];

        f32x4 acc[2][8];
        #pragma unroll
        for (int t = 0; t < 2; ++t)
            #pragma unroll
            for (int u = 0; u < 8; ++u)
                acc[t][u] = (f32x4){0.f, 0.f, 0.f, 0.f};

        const _Float16* wl = Wc + l * 65536;
        #pragma unroll
        for (int kc = 0; kc < 8; ++kc) {
            __syncthreads();   // prior chunk's B-reads done before overwrite
            {
                const _Float16* src = wl + kc * 8192 + wv * 2048 + lane * 8;
                _Float16* dst = &wlds[wv * 2048];   // wave-uniform; HW adds lane*16B
                #pragma unroll
                for (int i = 0; i < 4; ++i)
                    gload_lds16(src + i * 512, dst + i * 512);
            }
            __syncthreads();   // staging visible (emits vmcnt(0) drain)

            // B-frag: B[k][n] = W[n][k]; lane holds row n=lane&15(+16u), k=(lane>>4)*8..+8
            half8 bfr[8];
            #pragma unroll
            for (int u = 0; u < 8; ++u)
                bfr[u] = *(const half8*)&wlds[(nh * 128 + u * 16 + l15) * 32 + l4 * 8];
            #pragma unroll
            for (int u = 0; u < 8; ++u) {
                acc[0][u] = __builtin_amdgcn_mfma_f32_16x16x32_f16(afr[0][kc], bfr[u], acc[0][u], 0, 0, 0);
                acc[1][u] = __builtin_amdgcn_mfma_f32_16x16x32_f16(afr[1][kc], bfr[u], acc[1][u], 0, 0, 0);
            }
        }

        // Epilogue: bias + sin -> f16 back into hbuf (wave-exclusive 32x128 region).
        // C/D mapping (16x16x32): col = lane&15, row = (lane>>4)*4 + reg
        const float* bl = biases[l];
        #pragma unroll
        for (int u = 0; u < 8; ++u) {
            const int n = nh * 128 + u * 16 + l15;
            const float bb = bl[n];
            #pragma unroll
            for (int t = 0; t < 2; ++t) {
                const int m0 = mh * 32 + t * 16 + l4 * 4;
                #pragma unroll
                for (int r = 0; r < 4; ++r) {
                    float z = acc[t][u][r] + bb;
                    hbuf[(m0 + r) * WPAD + n] = (_Float16)__sinf(z);
                }
            }
        }
        __syncthreads();   // h complete before next layer's A-preload / final dot
    }

    // ---- final layer: out[m] = h[m,:] . Wf + bf, 4 lanes per point ----
    {
        const int m = tid >> 2, q = tid & 3;
        const _Float16* hrow = &hbuf[m * WPAD + q * 64];
        float sum = 0.f;
        #pragma unroll
        for (int i = 0; i < 8; ++i) {
            half8 hv = *(const half8*)&hrow[i * 8];
            const int nb = q * 64 + i * 8;
            #pragma unroll
            for (int j = 0; j < 8; ++j)
                sum = fmaf((float)hv[j], wf_s[nb + j], sum);
        }
        sum += __shfl_down(sum, 2);
        sum += __shfl_down(sum, 1);
        if (q == 0) out[gm0 + m] = sum + bfin[0];
    }
}

extern "C" void kernel_launch(void* const* d_in, const int* in_sizes, int n_in,
                              void* d_out, int out_size, void* d_ws, size_t ws_size,
                              hipStream_t stream) {
    const float* xyt = (const float*)d_in[0];
    const float* W0  = (const float*)d_in[1];
    const float* b0  = (const float*)d_in[2];
    const float* W1  = (const float*)d_in[3];
    const float* b1  = (const float*)d_in[4];
    const float* W2  = (const float*)d_in[5];
    const float* b2  = (const float*)d_in[6];
    const float* W3  = (const float*)d_in[7];
    const float* b3  = (const float*)d_in[8];
    const float* W4  = (const float*)d_in[9];
    const float* b4  = (const float*)d_in[10];
    const float* Wf  = (const float*)d_in[11];
    const float* bf  = (const float*)d_in[12];
    float* out = (float*)d_out;
    _Float16* Wc = (_Float16*)d_ws;    // 4 * 65536 f16 = 512 KB

    convert_weights<<<1024, 256, 0, stream>>>(W1, W2, W3, W4, Wc);

    const int N = in_sizes[0] / 3;     // 1048576
    siren_fused<<<N / 64, 256, 0, stream>>>(xyt, W0, b0, Wc, b1, b2, b3, b4, Wf, bf, out);
}

// Round 2
// 823.579 us; speedup vs baseline: 1.0091x; 1.0091x over previous
//
#include <hip/hip_runtime.h>

typedef _Float16 half8 __attribute__((ext_vector_type(8)));
typedef _Float16 half4 __attribute__((ext_vector_type(4)));
typedef float f32x4 __attribute__((ext_vector_type(4)));

#define WPAD 264      // 128-row hbuf stride: 528 B = 33*16 (b128-aligned, stride%32dw=4 -> conflict-free)
#define NPB 128       // points per block
#define THREADS 512
#define SMEM_BYTES 102912   // hbuf 67584 + wlds 32768 + xs 1536 + wf 1024

__device__ __forceinline__ void gload_lds16(const _Float16* g, _Float16* l) {
    __builtin_amdgcn_global_load_lds(
        (__attribute__((address_space(1))) void*)(void*)(g),
        (__attribute__((address_space(3))) void*)(void*)(l), 16, 0, 0);
}

// Repack W1..W4 fp32 [256x256] row-major -> f16 chunk-major [kc][n][kl] (kc=k/32, kl=k%32):
// each 16KB K-chunk contiguous for global_load_lds staging.
__global__ void convert_weights(const float* __restrict__ W1, const float* __restrict__ W2,
                                const float* __restrict__ W3, const float* __restrict__ W4,
                                _Float16* __restrict__ Wc) {
    int tid = blockIdx.x * 256 + threadIdx.x;      // 0 .. 262143
    int l   = tid >> 16;
    int rem = tid & 65535;
    int n = rem >> 8, k = rem & 255;
    const float* W = (l == 0) ? W1 : (l == 1) ? W2 : (l == 2) ? W3 : W4;
    int kc = k >> 5, kl = k & 31;
    Wc[l * 65536 + kc * 8192 + n * 32 + kl] = (_Float16)W[rem];
}

__launch_bounds__(THREADS, 2)
__global__ void siren_fused(const float* __restrict__ xyt,
                            const float* __restrict__ W0,
                            const float* __restrict__ b0,
                            const _Float16* __restrict__ Wc,
                            const float* __restrict__ b1,
                            const float* __restrict__ b2,
                            const float* __restrict__ b3,
                            const float* __restrict__ b4,
                            const float* __restrict__ Wf,
                            const float* __restrict__ bfin,
                            float* __restrict__ out)
{
    extern __shared__ _Float16 smem[];
    _Float16* hbuf = smem;                       // [NPB][WPAD] f16, 67584 B
    _Float16* wlds = smem + NPB * WPAD;          // 2 x 8192 f16 (16 KB each)
    float* xs   = (float*)(smem + NPB * WPAD + 16384);   // 384 f32
    float* wf_s = xs + 384;                      // 256 f32

    const int tid  = threadIdx.x;
    const int lane = tid & 63;
    const int wv   = tid >> 6;       // wave 0..7
    const int l15  = lane & 15;
    const int l4   = lane >> 4;
    const int mq   = wv & 3;         // m-quarter: 32 points
    const int nh   = wv >> 2;        // n_out half: 128 features
    const int gm0  = blockIdx.x * NPB;

    if (tid < 384) xs[tid] = xyt[gm0 * 3 + tid];
    if (tid < 256) wf_s[tid] = Wf[tid];
    __syncthreads();

    // Kick off staging of (layer 0 hidden, kc=0) into buf0 — hidden behind layer-0 compute.
    {
        const _Float16* src = Wc + (wv * 2) * 512 + lane * 8;
        _Float16* dst = wlds + (wv * 2) * 512;   // wave-uniform base; HW adds lane*16B
        gload_lds16(src, dst);
        gload_lds16(src + 512, dst + 512);
    }

    // ---- layer 0: h = sin(30*(x @ W0^T + b0)), K=3, fp32 VALU ----
    {
        const int n   = tid & 255;
        const int mh0 = tid >> 8;
        const float w0x = W0[n * 3], w0y = W0[n * 3 + 1], w0z = W0[n * 3 + 2];
        const float bb = b0[n];
        #pragma unroll 4
        for (int mi = 0; mi < 64; ++mi) {
            int m = mh0 * 64 + mi;
            float z = 30.0f * fmaf(w0x, xs[m * 3],
                          fmaf(w0y, xs[m * 3 + 1],
                          fmaf(w0z, xs[m * 3 + 2], bb)));
            hbuf[m * WPAD + n] = (_Float16)__sinf(z);
        }
    }

    // ---- 4 hidden layers, swapped orientation: D[n_out][m] = W h^T, MFMA f16 ----
    int p = 0;
    for (int l = 0; l < 4; ++l) {
        const float* bl = (l == 0) ? b1 : (l == 1) ? b2 : (l == 2) ? b3 : b4;

        f32x4 acc[8][2];
        #pragma unroll
        for (int i = 0; i < 8; ++i) {
            acc[i][0] = (f32x4){0.f, 0.f, 0.f, 0.f};
            acc[i][1] = (f32x4){0.f, 0.f, 0.f, 0.f};
        }
        half8 bfr[2][8];   // this wave's 32 points x K=256 activations (64 VGPRs)

        #pragma unroll
        for (int kc = 0; kc < 8; ++kc) {
            // buf[p] loads complete + (kc==0) hbuf from previous layer visible
            __syncthreads();

            // issue next chunk into buf[1-p] (ages one compute phase before its barrier)
            if (!(l == 3 && kc == 7)) {
                int nl = l, nkc = kc + 1;
                if (nkc == 8) { nl = l + 1; nkc = 0; }
                const _Float16* src = Wc + (nl * 8 + nkc) * 8192 + (wv * 2) * 512 + lane * 8;
                _Float16* dst = wlds + (1 - p) * 8192 + (wv * 2) * 512;
                gload_lds16(src, dst);
                gload_lds16(src + 512, dst + 512);
            }

            if (kc == 0) {
                // B-preload: B[k][j=m] = h[m][k]; per lane fixed m = mq*32+j*16+l15, 8 consecutive k
                #pragma unroll
                for (int j = 0; j < 2; ++j)
                    #pragma unroll
                    for (int c = 0; c < 8; ++c)
                        bfr[j][c] = *(const half8*)&hbuf[(mq * 32 + j * 16 + l15) * WPAD + c * 32 + l4 * 8];
            }

            // A = W chunk: per lane fixed row n_out = nh*128+i*16+l15, 8 consecutive k
            const _Float16* wb = wlds + p * 8192;
            #pragma unroll
            for (int i = 0; i < 8; ++i) {
                half8 af = *(const half8*)&wb[(nh * 128 + i * 16 + l15) * 32 + l4 * 8];
                acc[i][0] = __builtin_amdgcn_mfma_f32_16x16x32_f16(af, bfr[0][kc], acc[i][0], 0, 0, 0);
                acc[i][1] = __builtin_amdgcn_mfma_f32_16x16x32_f16(af, bfr[1][kc], acc[i][1], 0, 0, 0);
            }
            p ^= 1;
        }

        // Epilogue: C-layout col = m (lane&15), row = n_out = nh*128 + i*16 + l4*4 + r.
        // 4 consecutive n_out per reg quad -> packed half4 store into hbuf[m][n_out].
        #pragma unroll
        for (int i = 0; i < 8; ++i) {
            f32x4 bb = ((const f32x4*)bl)[nh * 32 + i * 4 + l4];
            #pragma unroll
            for (int j = 0; j < 2; ++j) {
                half4 hv;
                #pragma unroll
                for (int r = 0; r < 4; ++r)
                    hv[r] = (_Float16)__sinf(acc[i][j][r] + bb[r]);
                *(half4*)&hbuf[(mq * 32 + j * 16 + l15) * WPAD + nh * 128 + i * 16 + l4 * 4] = hv;
            }
        }
        // no layer-end barrier needed: next layer's kc=0 barrier publishes hbuf before B-preload
    }

    __syncthreads();   // final hbuf visible

    // ---- final layer: out[m] = h[m,:] . Wf + bf, 4 lanes per point ----
    {
        const int m = tid >> 2, q = tid & 3;
        const _Float16* hrow = &hbuf[m * WPAD + q * 64];
        float sum = 0.f;
        #pragma unroll
        for (int i = 0; i < 8; ++i) {
            half8 hv = *(const half8*)&hrow[i * 8];
            const int nb = q * 64 + i * 8;
            #pragma unroll
            for (int j = 0; j < 8; ++j)
                sum = fmaf((float)hv[j], wf_s[nb + j], sum);
        }
        sum += __shfl_down(sum, 2);
        sum += __shfl_down(sum, 1);
        if (q == 0) out[gm0 + m] = sum + bfin[0];
    }
}

extern "C" void kernel_launch(void* const* d_in, const int* in_sizes, int n_in,
                              void* d_out, int out_size, void* d_ws, size_t ws_size,
                              hipStream_t stream) {
    const float* xyt = (const float*)d_in[0];
    const float* W0  = (const float*)d_in[1];
    const float* b0  = (const float*)d_in[2];
    const float* W1  = (const float*)d_in[3];
    const float* b1  = (const float*)d_in[4];
    const float* W2  = (const float*)d_in[5];
    const float* b2  = (const float*)d_in[6];
    const float* W3  = (const float*)d_in[7];
    const float* b3  = (const float*)d_in[8];
    const float* W4  = (const float*)d_in[9];
    const float* b4  = (const float*)d_in[10];
    const float* Wf  = (const float*)d_in[11];
    const float* bf  = (const float*)d_in[12];
    float* out = (float*)d_out;
    _Float16* Wc = (_Float16*)d_ws;    // 4 * 65536 f16 = 512 KB

    // allow >64KB dynamic LDS (host-side attribute; legal under graph capture, idempotent)
    hipFuncSetAttribute((const void*)siren_fused,
                        hipFuncAttributeMaxDynamicSharedMemorySize, SMEM_BYTES);

    convert_weights<<<1024, 256, 0, stream>>>(W1, W2, W3, W4, Wc);

    const int N = in_sizes[0] / 3;     // 1048576
    siren_fused<<<N / NPB, THREADS, SMEM_BYTES, stream>>>(
        xyt, W0, b0, Wc, b1, b2, b3, b4, Wf, bf, out);
}

// Round 3
// 730.049 us; speedup vs baseline: 1.1383x; 1.1281x over previous
//
#include <hip/hip_runtime.h>

typedef _Float16 half8 __attribute__((ext_vector_type(8)));
typedef _Float16 half4 __attribute__((ext_vector_type(4)));
typedef float f32x4 __attribute__((ext_vector_type(4)));

#define WPAD 264      // hbuf row stride in f16: 528 B, 16B-aligned, stride%128B != 0
#define NPB 64        // points per block
#define THREADS 256

// Repack W1..W4 fp32 [256x256] row-major -> f16 chunk-major [kc][n][kl] (kc=k/32, kl=k%32):
// within a chunk, a wave's 64 feature rows are 4KB contiguous; lane reads are b128-coalesced.
__global__ void convert_weights(const float* __restrict__ W1, const float* __restrict__ W2,
                                const float* __restrict__ W3, const float* __restrict__ W4,
                                _Float16* __restrict__ Wc) {
    int tid = blockIdx.x * 256 + threadIdx.x;      // 0 .. 262143
    int l   = tid >> 16;
    int rem = tid & 65535;
    int n = rem >> 8, k = rem & 255;
    const float* W = (l == 0) ? W1 : (l == 1) ? W2 : (l == 2) ? W3 : W4;
    int kc = k >> 5, kl = k & 31;
    Wc[l * 65536 + kc * 8192 + n * 32 + kl] = (_Float16)W[rem];
}

__launch_bounds__(THREADS, 2)
__global__ void siren_fused(const float* __restrict__ xyt,
                            const float* __restrict__ W0,
                            const float* __restrict__ b0,
                            const _Float16* __restrict__ Wc,
                            const float* __restrict__ b1,
                            const float* __restrict__ b2,
                            const float* __restrict__ b3,
                            const float* __restrict__ b4,
                            const float* __restrict__ Wf,
                            const float* __restrict__ bfin,
                            float* __restrict__ out)
{
    __shared__ _Float16 hbuf[NPB * WPAD];   // activations, 33792 B
    __shared__ float    xs[NPB * 3];
    __shared__ float    wf_s[256];

    const int tid  = threadIdx.x;
    const int lane = tid & 63;
    const int wv   = tid >> 6;       // wave 0..3; owns features [wv*64, wv*64+64)
    const int l15  = lane & 15;
    const int l4   = lane >> 4;
    const int gm0  = blockIdx.x * NPB;

    if (tid < NPB * 3) xs[tid] = xyt[gm0 * 3 + tid];
    wf_s[tid] = Wf[tid];
    __syncthreads();

    // ---- layer 0: h = sin(30*(x @ W0^T + b0)), K=3, fp32 VALU ----
    {
        const int n = tid;
        const float w0x = W0[n * 3], w0y = W0[n * 3 + 1], w0z = W0[n * 3 + 2];
        const float bb = b0[n];
        #pragma unroll 8
        for (int m = 0; m < NPB; ++m) {
            float z = 30.0f * fmaf(w0x, xs[m * 3],
                          fmaf(w0y, xs[m * 3 + 1],
                          fmaf(w0z, xs[m * 3 + 2], bb)));
            hbuf[m * WPAD + n] = (_Float16)__sinf(z);
        }
    }
    // no barrier here: the layer loop's first barrier publishes hbuf

    // lane's base offset within any K-chunk (i adds 16 rows = 512 f16)
    const int arow = (wv * 64 + l15) * 32 + l4 * 8;

    // A-ring: W chunks in registers, depth 4 (64 VGPR). Fine-grained vmcnt waits,
    // no LDS staging, no barrier-coupled drains.
    half8 areg[4][4];
    {
        const _Float16* wl = Wc;   // layer l=0 (W1)
        #pragma unroll
        for (int c = 0; c < 4; ++c)
            #pragma unroll
            for (int i = 0; i < 4; ++i)
                areg[c][i] = *(const half8*)&wl[c * 8192 + arow + i * 512];
    }

    #pragma unroll
    for (int l = 0; l < 4; ++l) {
        const float* bl = (l == 0) ? b1 : (l == 1) ? b2 : (l == 2) ? b3 : b4;

        __syncthreads();   // hbuf from previous layer stable

        // B-preload: this wave's view of ALL 64 points x K=256 (64 VGPR).
        // B-frag: lane holds point m = j*16 + l15, k = l4*8 .. +8 (per chunk c)
        half8 bfr[4][8];
        #pragma unroll
        for (int j = 0; j < 4; ++j)
            #pragma unroll
            for (int c = 0; c < 8; ++c)
                bfr[j][c] = *(const half8*)&hbuf[(j * 16 + l15) * WPAD + c * 32 + l4 * 8];

        __syncthreads();   // all waves done READING hbuf -> epilogue may overwrite

        f32x4 acc[4][4];
        #pragma unroll
        for (int i = 0; i < 4; ++i)
            #pragma unroll
            for (int j = 0; j < 4; ++j)
                acc[i][j] = (f32x4){0.f, 0.f, 0.f, 0.f};

        const _Float16* wl = Wc + l * 65536;
        #pragma unroll
        for (int kc = 0; kc < 8; ++kc) {
            // MFMA: A = W rows (M-dim = features), B = h^T (N-dim = points)
            #pragma unroll
            for (int i = 0; i < 4; ++i) {
                half8 af = areg[kc & 3][i];
                #pragma unroll
                for (int j = 0; j < 4; ++j)
                    acc[i][j] = __builtin_amdgcn_mfma_f32_16x16x32_f16(af, bfr[j][kc], acc[i][j], 0, 0, 0);
            }
            // prefetch chunk kc+4 into the slot just consumed (3-chunk distance)
            if (kc < 4) {
                #pragma unroll
                for (int i = 0; i < 4; ++i)
                    areg[kc & 3][i] = *(const half8*)&wl[(kc + 4) * 8192 + arow + i * 512];
            }
        }

        // issue next layer's prologue A-loads before the epilogue math (overlap)
        if (l < 3) {
            const _Float16* wn = Wc + (l + 1) * 65536;
            #pragma unroll
            for (int c = 0; c < 4; ++c)
                #pragma unroll
                for (int i = 0; i < 4; ++i)
                    areg[c][i] = *(const half8*)&wn[c * 8192 + arow + i * 512];
        }

        // Epilogue: C-layout col = point m (lane&15), row = feature = l4*4 + r (+i*16 +wv*64).
        // 4 consecutive features per reg quad -> packed half4 store.
        #pragma unroll
        for (int i = 0; i < 4; ++i) {
            f32x4 bb = ((const f32x4*)bl)[wv * 16 + i * 4 + l4];
            #pragma unroll
            for (int j = 0; j < 4; ++j) {
                half4 hv;
                #pragma unroll
                for (int r = 0; r < 4; ++r)
                    hv[r] = (_Float16)__sinf(acc[i][j][r] + bb[r]);
                *(half4*)&hbuf[(j * 16 + l15) * WPAD + wv * 64 + i * 16 + l4 * 4] = hv;
            }
        }
        // next layer's first barrier publishes these writes
    }

    __syncthreads();   // final hbuf visible

    // ---- final layer: out[m] = h[m,:] . Wf + bf, 4 lanes per point ----
    {
        const int m = tid >> 2, q = tid & 3;
        const _Float16* hrow = &hbuf[m * WPAD + q * 64];
        float sum = 0.f;
        #pragma unroll
        for (int i = 0; i < 8; ++i) {
            half8 hv = *(const half8*)&hrow[i * 8];
            const int nb = q * 64 + i * 8;
            #pragma unroll
            for (int j = 0; j < 8; ++j)
                sum = fmaf((float)hv[j], wf_s[nb + j], sum);
        }
        sum += __shfl_down(sum, 2);
        sum += __shfl_down(sum, 1);
        if (q == 0) out[gm0 + m] = sum + bfin[0];
    }
}

extern "C" void kernel_launch(void* const* d_in, const int* in_sizes, int n_in,
                              void* d_out, int out_size, void* d_ws, size_t ws_size,
                              hipStream_t stream) {
    const float* xyt = (const float*)d_in[0];
    const float* W0  = (const float*)d_in[1];
    const float* b0  = (const float*)d_in[2];
    const float* W1  = (const float*)d_in[3];
    const float* b1  = (const float*)d_in[4];
    const float* W2  = (const float*)d_in[5];
    const float* b2  = (const float*)d_in[6];
    const float* W3  = (const float*)d_in[7];
    const float* b3  = (const float*)d_in[8];
    const float* W4  = (const float*)d_in[9];
    const float* b4  = (const float*)d_in[10];
    const float* Wf  = (const float*)d_in[11];
    const float* bf  = (const float*)d_in[12];
    float* out = (float*)d_out;
    _Float16* Wc = (_Float16*)d_ws;    // 4 * 65536 f16 = 512 KB

    convert_weights<<<1024, 256, 0, stream>>>(W1, W2, W3, W4, Wc);

    const int N = in_sizes[0] / 3;     // 1048576
    siren_fused<<<N / NPB, THREADS, 0, stream>>>(
        xyt, W0, b0, Wc, b1, b2, b3, b4, Wf, bf, out);
}

// Round 4
// 620.621 us; speedup vs baseline: 1.3391x; 1.1763x over previous
//
#include <hip/hip_runtime.h>

typedef _Float16 half8 __attribute__((ext_vector_type(8)));
typedef _Float16 half4 __attribute__((ext_vector_type(4)));
typedef float f32x4 __attribute__((ext_vector_type(4)));

#define WPAD 264      // hbuf row stride (f16): 528 B = 33*16, b128-aligned, conflict-benign
#define NPB 128       // points per block
#define THREADS 512   // 8 waves; wave owns 32 features x all 128 points
#define INV2PI 0.15915494309189535f
#define W0SCALE (30.0f * INV2PI)
#define SMEM_BYTES (NPB * WPAD * 2 + (384 + 256) * 4)   // 70144 B -> 2 blocks/CU

// Repack W1..W4 fp32 [256x256] row-major -> f16 chunk-major [kc][n][kl] (kc=k/32, kl=k%32),
// PRESCALED by 1/(2*pi) so the epilogue sine is a bare v_sin_f32 (input in revolutions).
__global__ void convert_weights(const float* __restrict__ W1, const float* __restrict__ W2,
                                const float* __restrict__ W3, const float* __restrict__ W4,
                                _Float16* __restrict__ Wc) {
    int tid = blockIdx.x * 256 + threadIdx.x;      // 0 .. 262143
    int l   = tid >> 16;
    int rem = tid & 65535;
    int n = rem >> 8, k = rem & 255;
    const float* W = (l == 0) ? W1 : (l == 1) ? W2 : (l == 2) ? W3 : W4;
    int kc = k >> 5, kl = k & 31;
    Wc[l * 65536 + kc * 8192 + n * 32 + kl] = (_Float16)(W[rem] * INV2PI);
}

__launch_bounds__(THREADS, 4)
__global__ void siren_fused(const float* __restrict__ xyt,
                            const float* __restrict__ W0,
                            const float* __restrict__ b0,
                            const _Float16* __restrict__ Wc,
                            const float* __restrict__ b1,
                            const float* __restrict__ b2,
                            const float* __restrict__ b3,
                            const float* __restrict__ b4,
                            const float* __restrict__ Wf,
                            const float* __restrict__ bfin,
                            float* __restrict__ out)
{
    extern __shared__ _Float16 smem[];
    _Float16* hbuf = smem;                           // [NPB][WPAD] f16, 67584 B
    float* xs   = (float*)(smem + NPB * WPAD);       // 384 f32
    float* wf_s = xs + 384;                          // 256 f32

    const int tid  = threadIdx.x;
    const int lane = tid & 63;
    const int wv   = tid >> 6;       // wave 0..7; owns features [wv*32, wv*32+32)
    const int l15  = lane & 15;
    const int l4   = lane >> 4;
    const int gm0  = blockIdx.x * NPB;

    if (tid < 384) xs[tid] = xyt[gm0 * 3 + tid];
    if (tid < 256) wf_s[tid] = Wf[tid];
    __syncthreads();

    // ---- layer 0: h = sin(30*(x @ W0^T + b0)); prescaled -> bare v_sin; packed b64 writes ----
    {
        const int fg = lane;          // features 4*lane .. 4*lane+3
        const int p0 = wv * 16;       // this wave's 16 points
        float w[4][3], bb[4];
        #pragma unroll
        for (int c = 0; c < 4; ++c) {
            const int n = fg * 4 + c;
            w[c][0] = W0[n * 3 + 0] * W0SCALE;
            w[c][1] = W0[n * 3 + 1] * W0SCALE;
            w[c][2] = W0[n * 3 + 2] * W0SCALE;
            bb[c]   = b0[n] * W0SCALE;
        }
        #pragma unroll 4
        for (int p = 0; p < 16; ++p) {
            const float x0 = xs[(p0 + p) * 3], x1 = xs[(p0 + p) * 3 + 1], x2 = xs[(p0 + p) * 3 + 2];
            half4 hv;
            #pragma unroll
            for (int c = 0; c < 4; ++c) {
                float z = fmaf(w[c][0], x0, fmaf(w[c][1], x1, fmaf(w[c][2], x2, bb[c])));
                hv[c] = (_Float16)__builtin_amdgcn_sinf(z);   // z in revolutions
            }
            *(half4*)&hbuf[(p0 + p) * WPAD + fg * 4] = hv;
        }
    }

    // lane's byte-invariant A offset within any 16KB K-chunk (i adds 16 rows = 512 f16)
    const int arow = (wv * 32 + l15) * 32 + l4 * 8;

    // ---- 4 hidden layers: D[feat][pt] = W' h^T (MFMA f16), sin via v_sin, bias in acc init ----
    #pragma unroll
    for (int l = 0; l < 4; ++l) {
        const float* bl = (l == 0) ? b1 : (l == 1) ? b2 : (l == 2) ? b3 : b4;
        const _Float16* wl = Wc + l * 65536;

        // A-ring prologue (kc=0,1) + bias loads: issued BEFORE the barrier (latency hidden by it)
        half8 areg[2][2];
        #pragma unroll
        for (int c = 0; c < 2; ++c)
            #pragma unroll
            for (int i = 0; i < 2; ++i)
                areg[c][i] = *(const half8*)&wl[c * 8192 + arow + i * 512];

        f32x4 acc[2][8];
        #pragma unroll
        for (int i = 0; i < 2; ++i) {
            f32x4 bb = *(const f32x4*)&bl[wv * 32 + i * 16 + l4 * 4];
            bb *= INV2PI;
            #pragma unroll
            for (int j = 0; j < 8; ++j)
                acc[i][j] = bb;       // bias folded into accumulator init (prescaled)
        }

        __syncthreads();   // hbuf from previous layer stable

        #pragma unroll
        for (int kc = 0; kc < 8; ++kc) {
            // prefetch A chunk kc+2 (covers ~2 MFMA phases of L2 latency)
            half8 anext[2];
            if (kc < 6) {
                #pragma unroll
                for (int i = 0; i < 2; ++i)
                    anext[i] = *(const half8*)&wl[(kc + 2) * 8192 + arow + i * 512];
            }
            // B from LDS in-loop (single vaddr + imm offsets), two half-groups to cap live regs
            #pragma unroll
            for (int g = 0; g < 2; ++g) {
                half8 bfr[4];
                #pragma unroll
                for (int j = 0; j < 4; ++j)
                    bfr[j] = *(const half8*)&hbuf[((g * 4 + j) * 16 + l15) * WPAD + kc * 32 + l4 * 8];
                #pragma unroll
                for (int i = 0; i < 2; ++i)
                    #pragma unroll
                    for (int j = 0; j < 4; ++j)
                        acc[i][g * 4 + j] = __builtin_amdgcn_mfma_f32_16x16x32_f16(
                            areg[kc & 1][i], bfr[j], acc[i][g * 4 + j], 0, 0, 0);
            }
            if (kc < 6) { areg[kc & 1][0] = anext[0]; areg[kc & 1][1] = anext[1]; }
        }

        __syncthreads();   // all waves' B-reads done -> safe to overwrite hbuf

        // Epilogue: C-layout col = point (lane&15), feature = wv*32 + i*16 + l4*4 + r.
        // acc already holds (W h + b)/(2pi): one v_sin per value, packed half4 store.
        #pragma unroll
        for (int i = 0; i < 2; ++i)
            #pragma unroll
            for (int j = 0; j < 8; ++j) {
                half4 hv;
                #pragma unroll
                for (int r = 0; r < 4; ++r)
                    hv[r] = (_Float16)__builtin_amdgcn_sinf(acc[i][j][r]);
                *(half4*)&hbuf[(j * 16 + l15) * WPAD + wv * 32 + i * 16 + l4 * 4] = hv;
            }
        // next layer's first barrier publishes these writes
    }

    __syncthreads();   // final hbuf visible

    // ---- final layer: out[m] = h[m,:] . Wf + bf, 4 lanes per point ----
    {
        const int m = tid >> 2, q = tid & 3;
        const _Float16* hrow = &hbuf[m * WPAD + q * 64];
        float sum = 0.f;
        #pragma unroll
        for (int i = 0; i < 8; ++i) {
            half8 hv = *(const half8*)&hrow[i * 8];
            const int nb = q * 64 + i * 8;
            #pragma unroll
            for (int j = 0; j < 8; ++j)
                sum = fmaf((float)hv[j], wf_s[nb + j], sum);
        }
        sum += __shfl_down(sum, 2);
        sum += __shfl_down(sum, 1);
        if (q == 0) out[gm0 + m] = sum + bfin[0];
    }
}

extern "C" void kernel_launch(void* const* d_in, const int* in_sizes, int n_in,
                              void* d_out, int out_size, void* d_ws, size_t ws_size,
                              hipStream_t stream) {
    const float* xyt = (const float*)d_in[0];
    const float* W0  = (const float*)d_in[1];
    const float* b0  = (const float*)d_in[2];
    const float* W1  = (const float*)d_in[3];
    const float* b1  = (const float*)d_in[4];
    const float* W2  = (const float*)d_in[5];
    const float* b2  = (const float*)d_in[6];
    const float* W3  = (const float*)d_in[7];
    const float* b3  = (const float*)d_in[8];
    const float* W4  = (const float*)d_in[9];
    const float* b4  = (const float*)d_in[10];
    const float* Wf  = (const float*)d_in[11];
    const float* bf  = (const float*)d_in[12];
    float* out = (float*)d_out;
    _Float16* Wc = (_Float16*)d_ws;    // 4 * 65536 f16 = 512 KB

    hipFuncSetAttribute((const void*)siren_fused,
                        hipFuncAttributeMaxDynamicSharedMemorySize, SMEM_BYTES);

    convert_weights<<<1024, 256, 0, stream>>>(W1, W2, W3, W4, Wc);

    const int N = in_sizes[0] / 3;     // 1048576
    siren_fused<<<N / NPB, THREADS, SMEM_BYTES, stream>>>(
        xyt, W0, b0, Wc, b1, b2, b3, b4, Wf, bf, out);
}